// Round 1
// 84.753 us; speedup vs baseline: 1.1095x; 1.1095x over previous
//
#include <hip/hip_runtime.h>

// DeformConv2D b=4,c=128,H=W=64,outc=128,KS=3,PAD=1,N=9
// 2-launch pipeline (mode 3), round-6: full-K merged (no split-K, no atomics):
//   prep  : wfrag32 + xpose fused, branch on blockIdx (1096 blocks; zero pass removed)
//   fullk : grid 512 = b4*i64*jh2 (XCD-swizzled), block = 32px x 128o,
//           256 thr (4 waves; wave = 32o x 32px via mfma_f32_32x32x16_bf16).
//           Phase 0: all 288 descs computed inline -> LDS.
//           3 kh-phases: stage taps {3t..3t+2} (register-batched quarter-wave
//           dwordx4 gathers) -> barrier -> 24 MFMA (acc carried across phases)
//           -> barrier. Epilogue: plain coalesced stores (out written once).
// Rationale: old splitk issued 6.3M device-scope f32 atomicAdds (cross-XCD
// coherence-point RMW) + needed an 8.4MB zero pass; both eliminated here.
// Fallback (mode<=2): round-5 fused kernel (verified, 16x16x32 path).

typedef __bf16  v8bf16 __attribute__((ext_vector_type(8)));
typedef __bf16  bf16x2 __attribute__((ext_vector_type(2)));
typedef float   f32x4  __attribute__((ext_vector_type(4)));
typedef float   f32x16 __attribute__((ext_vector_type(16)));
typedef unsigned short ushort4v __attribute__((ext_vector_type(4)));
typedef _Float16 half4v __attribute__((ext_vector_type(4)));

#define CIN  128
#define NPT  9
#define KTOT 1152
#define OC   128
#define PX   32
#define NDESC (NPT * PX)     // 288
#define KSTEPS 36            // 16x16x32 steps (fallback layout)
#define KSC  12
#define LDBc 392
#define KS32 72              // 32x32x16 K-steps of 16 (mode-3 layout)
#define KSC32 24             // per kh
#define LDR32 392            // Bt row stride bf16: 384 + 8

// prep grid layout (zero pass removed — fullk writes every output element)
#define PB_WFRAG 72              // 72*256 = 18432 = 4*72*64
#define PB_XPOSE 1024
#define PB_TOTAL (PB_WFRAG + PB_XPOSE)

// geometry -> packed descriptor {idx4 u16, g4 f16}
__device__ __forceinline__ uint4 desc_make(const float* __restrict__ off,
                                           int b, int i, int j, int tap) {
    float ox = off[(((b * 18) + 2 * tap) << 12) + (i << 6) + j];
    float oy = off[(((b * 18) + 2 * tap + 1) << 12) + (i << 6) + j];
    float px = (float)(i + tap / 3) + ox;
    float py = (float)(j + tap % 3) + oy;
    float fx = floorf(px), fy = floorf(py);
    int qltx = (int)fminf(fmaxf(fx, 0.f), 65.f);
    int qlty = (int)fminf(fmaxf(fy, 0.f), 65.f);
    int qrbx = (int)fminf(fmaxf(fx + 1.f, 0.f), 65.f);
    int qrby = (int)fminf(fmaxf(fy + 1.f, 0.f), 65.f);
    if (px < 1.f || px > 64.f) px = fx;
    if (py < 1.f || py > 64.f) py = fy;
    px = fminf(fmaxf(px, 0.f), 65.f);
    py = fminf(fmaxf(py, 0.f), 65.f);
    float wxl = 1.f + (float)qltx - px;
    float wxr = 1.f - ((float)qrbx - px);
    float wyl = 1.f + (float)qlty - py;
    float wyr = 1.f - ((float)qrby - py);
    float g[4] = { wxl * wyl, wxr * wyr, wxl * wyr, wxr * wyl };
    int qx[4] = { qltx, qrbx, qltx, qrbx };
    int qy[4] = { qlty, qrby, qrby, qlty };
    unsigned short idx[4];
    half4v gh;
    #pragma unroll
    for (int cr = 0; cr < 4; ++cr) {
        bool inb = (qx[cr] >= 1) && (qx[cr] <= 64) && (qy[cr] >= 1) && (qy[cr] <= 64);
        idx[cr] = inb ? (unsigned short)((qx[cr] - 1) * 64 + (qy[cr] - 1)) : 0;
        gh[cr]  = inb ? (_Float16)g[cr] : (_Float16)0.f;
    }
    uint4 rec;
    rec.x = (unsigned)idx[0] | ((unsigned)idx[1] << 16);
    rec.y = (unsigned)idx[2] | ((unsigned)idx[3] << 16);
    __builtin_memcpy(&rec.z, &gh, 8);
    return rec;
}

// ---------- fused prep: wfrag32 | xpose ----------
__global__ __launch_bounds__(256) void prep_kernel(
    const float* __restrict__ x, const float* __restrict__ w,
    __bf16* __restrict__ wfrag, __bf16* __restrict__ xt)
{
    __shared__ float tile[64][33];
    const int bid = blockIdx.x;
    const int tid = threadIdx.x;

    if (bid < PB_WFRAG) {
        // 32x32x16 A-frag layout: wfrag[((ot4*72+ks)*64+lane)*8+e]
        //   o = ot4*32 + (lane&31), k = ks*16 + (lane>>5)*8 + e
        int t = bid * 256 + tid;          // [0, 18432)
        int lane = t & 63;
        int ks   = (t >> 6) % KS32;
        int ot4  = t / (KS32 * 64);
        int o    = ot4 * 32 + (lane & 31);
        v8bf16 frag;
        #pragma unroll
        for (int e = 0; e < 8; ++e) {
            int k   = ks * 16 + ((lane >> 5) * 8) + e;
            int tap = k >> 7, c = k & 127;
            frag[e] = (__bf16)w[(size_t)o * KTOT + c * NPT + tap];
        }
        *(v8bf16*)(wfrag + (size_t)t * 8) = frag;
    } else {
        const int bidx = bid - PB_WFRAG;
        const int b   = bidx >> 8;
        const int hw0 = ((bidx >> 2) & 63) * 64;
        const int c0  = (bidx & 3) * 32;
        #pragma unroll
        for (int r = 0; r < 8; ++r) {
            int c_l  = (tid >> 6) + r * 4;
            int hw_l = tid & 63;
            tile[hw_l][c_l] = x[((size_t)(b * CIN + c0 + c_l) << 12) + hw0 + hw_l];
        }
        __syncthreads();
        #pragma unroll
        for (int r = 0; r < 8; ++r) {
            int hw_l = (tid >> 5) + r * 8;
            int c_l  = tid & 31;
            xt[((size_t)(b * 4096 + hw0 + hw_l)) * CIN + c0 + c_l] = (__bf16)tile[hw_l][c_l];
        }
    }
}

// ---------- full-K merged: inline desc, 3 kh-phases, 32x32x16 MFMA, plain stores ----------
__global__ __launch_bounds__(256) void fullk_kernel(
    const float* __restrict__ off, const __bf16* __restrict__ xt,
    const __bf16* __restrict__ wfrag, float* __restrict__ out)
{
    __shared__ __align__(16) __bf16 Bt[PX][LDR32];   // 32 x 392 bf16 = 25088 B
    __shared__ __align__(16) uint4 sDesc[NDESC];     // 288 descs = 4608 B

    // XCD swizzle: b rides the low bits (2 XCDs per batch -> xt L2-resident)
    const int bidx = blockIdx.x;     // [0, 512)
    const int b    = (bidx & 7) >> 1;
    const int sub  = ((bidx >> 3) << 1) | (bidx & 1);   // [0, 128)
    const int i    = sub >> 1;
    const int j0   = (sub & 1) * PX;
    const int tid  = threadIdx.x;

    const int l  = tid & 63;
    const int wv = tid >> 6;            // 0..3 -> 32-o tile

    const __bf16* xtb = xt + (((size_t)b << 12) * CIN);

    // ---- phase 0: all 288 descs (9 taps x 32 px) computed inline -> LDS ----
    {
        sDesc[tid] = desc_make(off, b, i, j0 + (tid & 31), tid >> 5);
        if (tid < 32) sDesc[256 + tid] = desc_make(off, b, i, j0 + tid, 8);
    }
    __syncthreads();

    f32x16 acc = {0.f,0.f,0.f,0.f,0.f,0.f,0.f,0.f,0.f,0.f,0.f,0.f,0.f,0.f,0.f,0.f};
    const __bf16* brow  = &Bt[l & 31][(l >> 5) * 8];
    const __bf16* warow = wfrag + (((size_t)wv * KS32) * 64 + l) * 8;

    const int q  = l >> 4;
    const int ll = l & 15;
    const __bf16* gbase = xtb + 8 * ll;

    for (int t = 0; t < 3; ++t) {
        // ---- stage 96 descs (taps 3t..3t+2), 24 per wave, register-batched
        //      quarter-wave dwordx4 gathers ----
        {
            uint4 qd[6];
            int   pp[6], tt[6];
            #pragma unroll
            for (int m = 0; m < 6; ++m) {
                int dl = wv * 24 + m * 4 + q;    // [0,96) local
                tt[m] = dl >> 5;
                pp[m] = dl & 31;
                qd[m] = sDesc[t * 96 + dl];
            }

            #pragma unroll
            for (int h = 0; h < 2; ++h) {
                uint4  v[3][4];
                half4v gh[3];
                #pragma unroll
                for (int m = 0; m < 3; ++m) {
                    uint4 qm = qd[h * 3 + m];
                    unsigned int zz[2] = { qm.z, qm.w };
                    __builtin_memcpy(&gh[m], &zz, 8);
                    unsigned short idx[4] = {
                        (unsigned short)(qm.x & 0xffff), (unsigned short)(qm.x >> 16),
                        (unsigned short)(qm.y & 0xffff), (unsigned short)(qm.y >> 16) };
                    #pragma unroll
                    for (int cr = 0; cr < 4; ++cr)
                        v[m][cr] = *(const uint4*)(gbase + (size_t)idx[cr] * CIN);
                }
                #pragma unroll
                for (int m = 0; m < 3; ++m) {
                    float s[8] = {0.f,0.f,0.f,0.f,0.f,0.f,0.f,0.f};
                    #pragma unroll
                    for (int cr = 0; cr < 4; ++cr) {
                        float gf = (float)gh[m][cr];
                        unsigned int dw[4] = { v[m][cr].x, v[m][cr].y, v[m][cr].z, v[m][cr].w };
                        #pragma unroll
                        for (int e = 0; e < 4; ++e) {
                            float clo, chi;
                            unsigned int lo = dw[e] << 16, hi = dw[e] & 0xffff0000u;
                            __builtin_memcpy(&clo, &lo, 4);
                            __builtin_memcpy(&chi, &hi, 4);
                            s[2 * e]     += gf * clo;
                            s[2 * e + 1] += gf * chi;
                        }
                    }
                    v8bf16 pr;
                    #pragma unroll
                    for (int e = 0; e < 8; ++e) pr[e] = (__bf16)s[e];
                    int mm = h * 3 + m;
                    *(v8bf16*)&Bt[pp[mm]][tt[mm] * CIN + 8 * ll] = pr;
                }
            }
        }
        __syncthreads();

        // ---- MFMA: wave wv = o-tile [wv*32, wv*32+32) x px [j0, j0+32),
        //      24 K-steps of 16, acc carried across the 3 kh-phases ----
        #pragma unroll 6
        for (int ks = 0; ks < KSC32; ++ks) {
            v8bf16 afrag = *(const v8bf16*)(warow + (size_t)(t * KSC32 + ks) * 64 * 8);
            v8bf16 bfrag = *(const v8bf16*)(brow + ks * 16);
            acc = __builtin_amdgcn_mfma_f32_32x32x16_bf16(afrag, bfrag, acc, 0, 0, 0);
        }
        if (t < 2) __syncthreads();   // Bt reused by next phase's staging
    }

    // ---- epilogue: px = l&31, o = wv*32 + 4*(l>>5) + (reg&3) + 8*(reg>>2) ----
    {
        int obase = wv * 32 + 4 * (l >> 5);
        float* opb = out + (((size_t)(b * OC + obase)) << 12) + (i << 6) + j0 + (l & 31);
        #pragma unroll
        for (int reg = 0; reg < 16; ++reg) {
            int oo = (reg & 3) + 8 * (reg >> 2);
            opb[(size_t)oo << 12] = acc[reg];
        }
    }
}

// ---------- round-5 fused fallback (verified) ----------
__global__ __launch_bounds__(512, 8) void deform_fused_kernel(
    const float* __restrict__ x, const float* __restrict__ off,
    const float* __restrict__ w, const __bf16* __restrict__ wfrag,
    const __bf16* __restrict__ xt, float* __restrict__ out, int mode)
{
    __shared__ __align__(16) __bf16 Bt[PX][LDBc];
    __shared__ __align__(8)  unsigned short sIdxP[NDESC][4];
    __shared__ __align__(8)  _Float16      sGP[NDESC][4];

    const int bidx = blockIdx.x;
    const int b   = bidx >> 8;
    const int i   = (bidx >> 2) & 63;
    const int j0  = ((bidx >> 1) & 1) * PX;
    const int oh  = bidx & 1;
    const int tid = threadIdx.x;

    if (tid < NDESC) {
        int k = tid >> 5, p = tid & 31;
        int j = j0 + p;
        float ox = off[(((b * 18) + 2 * k) * 64 + i) * 64 + j];
        float oy = off[(((b * 18) + 2 * k + 1) * 64 + i) * 64 + j];
        float px = (float)(i + k / 3) + ox;
        float py = (float)(j + k % 3) + oy;
        float fx = floorf(px), fy = floorf(py);
        int qltx = (int)fminf(fmaxf(fx, 0.f), 65.f);
        int qlty = (int)fminf(fmaxf(fy, 0.f), 65.f);
        int qrbx = (int)fminf(fmaxf(fx + 1.f, 0.f), 65.f);
        int qrby = (int)fminf(fmaxf(fy + 1.f, 0.f), 65.f);
        if (px < 1.f || px > 64.f) px = fx;
        if (py < 1.f || py > 64.f) py = fy;
        px = fminf(fmaxf(px, 0.f), 65.f);
        py = fminf(fmaxf(py, 0.f), 65.f);
        float wxl = 1.f + (float)qltx - px;
        float wxr = 1.f - ((float)qrbx - px);
        float wyl = 1.f + (float)qlty - py;
        float wyr = 1.f - ((float)qrby - py);
        float g[4] = { wxl * wyl, wxr * wyr, wxl * wyr, wxr * wyl };
        int qx[4] = { qltx, qrbx, qltx, qrbx };
        int qy[4] = { qlty, qrby, qrby, qlty };
        #pragma unroll
        for (int cr = 0; cr < 4; ++cr) {
            bool inb = (qx[cr] >= 1) && (qx[cr] <= 64) && (qy[cr] >= 1) && (qy[cr] <= 64);
            sIdxP[tid][cr] = inb ? (unsigned short)((qx[cr] - 1) * 64 + (qy[cr] - 1)) : 0;
            sGP[tid][cr]   = inb ? (_Float16)g[cr] : (_Float16)0.f;
        }
    }
    __syncthreads();

    const int l    = tid & 63;
    const int wv   = tid >> 6;
    const int ot   = oh * 4 + (wv & 3);
    const int ph   = wv >> 2;
    const int quad = l >> 4;
    const int lr   = l & 15;

    f32x4 acc = {0.f, 0.f, 0.f, 0.f};
    const __bf16* xtb = xt + ((size_t)b * 4096) * CIN;
    const float*  xb  = x + ((size_t)b * CIN << 12);
    const __bf16* brow = &Bt[ph * 16 + lr][quad * 8];

    for (int t = 0; t < 3; ++t) {
        if (mode == 2) {
            #pragma unroll 4
            for (int dd = 0; dd < KSC; ++dd) {
                int dl = wv * KSC + dd;
                int tap_l = dl >> 5, p = dl & 31;
                int d = t * 96 + dl;
                ushort4v id = *(const ushort4v*)&sIdxP[d][0];
                half4v   gh = *(const half4v*)&sGP[d][0];
                float s0 = 0.f, s1 = 0.f;
                #pragma unroll
                for (int cr = 0; cr < 4; ++cr) {
                    unsigned int v = *(const unsigned int*)(xtb + (size_t)id[cr] * CIN + 2 * l);
                    float c0v, c1v;
                    unsigned int lo = v << 16, hi = v & 0xffff0000u;
                    __builtin_memcpy(&c0v, &lo, 4);
                    __builtin_memcpy(&c1v, &hi, 4);
                    float gf = (float)gh[cr];
                    s0 += gf * c0v;
                    s1 += gf * c1v;
                }
                bf16x2 pr = { (__bf16)s0, (__bf16)s1 };
                *(bf16x2*)&Bt[p][tap_l * CIN + 2 * l] = pr;
            }
        } else {
            for (int dd = 0; dd < KSC; ++dd) {
                int dl = wv * KSC + dd;
                int tap_l = dl >> 5, p = dl & 31;
                int d = t * 96 + dl;
                ushort4v id = *(const ushort4v*)&sIdxP[d][0];
                half4v   gh = *(const half4v*)&sGP[d][0];
                float s0 = 0.f, s1 = 0.f;
                #pragma unroll
                for (int cr = 0; cr < 4; ++cr) {
                    float gf = (float)gh[cr];
                    s0 += gf * xb[((size_t)(2 * l) << 12) + id[cr]];
                    s1 += gf * xb[((size_t)(2 * l + 1) << 12) + id[cr]];
                }
                bf16x2 pr = { (__bf16)s0, (__bf16)s1 };
                *(bf16x2*)&Bt[p][tap_l * CIN + 2 * l] = pr;
            }
        }
        __syncthreads();

        #pragma unroll 4
        for (int ks = 0; ks < KSC; ++ks) {
            int ks_g = t * KSC + ks;
            v8bf16 bfrag = *(const v8bf16*)(brow + ks * 32);
            v8bf16 afrag;
            if (mode >= 1) {
                afrag = *(const v8bf16*)(wfrag + (((size_t)ot * KSTEPS + ks_g) * 64 + l) * 8);
            } else {
                int o = ot * 16 + lr;
                #pragma unroll
                for (int e = 0; e < 8; ++e) {
                    int k = ks_g * 32 + quad * 8 + e;
                    int tap = k >> 7, c = k & 127;
                    afrag[e] = (__bf16)w[(size_t)o * KTOT + c * NPT + tap];
                }
            }
            acc = __builtin_amdgcn_mfma_f32_16x16x32_bf16(afrag, bfrag, acc, 0, 0, 0);
        }
        if (t < 2) __syncthreads();
    }

    {
        int obase = ot * 16 + quad * 4;
        float* op = out + (((size_t)(b * OC + obase)) << 12) + (i << 6) + j0 + ph * 16 + lr;
        #pragma unroll
        for (int r = 0; r < 4; ++r)
            op[(size_t)r << 12] = acc[r];
    }
}

// standalone prep pieces for fallback modes (old 16x16x32 wfrag layout)
__global__ __launch_bounds__(256) void wfrag_kernel(const float* __restrict__ w,
                                                    __bf16* __restrict__ wfrag) {
    int t = blockIdx.x * 256 + threadIdx.x;
    if (t >= 8 * KSTEPS * 64) return;
    int lane = t & 63;
    int ks   = (t >> 6) % KSTEPS;
    int ot   = t / (KSTEPS * 64);
    int o    = ot * 16 + (lane & 15);
    v8bf16 frag;
    #pragma unroll
    for (int e = 0; e < 8; ++e) {
        int k   = ks * 32 + (lane >> 4) * 8 + e;
        int tap = k >> 7, c = k & 127;
        frag[e] = (__bf16)w[(size_t)o * KTOT + c * NPT + tap];
    }
    *(v8bf16*)(wfrag + (size_t)t * 8) = frag;
}

__global__ __launch_bounds__(256) void xpose_kernel(const float* __restrict__ x,
                                                    __bf16* __restrict__ xt) {
    __shared__ float tile[64][33];
    const int bidx = blockIdx.x;
    const int b   = bidx >> 8;
    const int hw0 = ((bidx >> 2) & 63) * 64;
    const int c0  = (bidx & 3) * 32;
    const int tid = threadIdx.x;
    #pragma unroll
    for (int r = 0; r < 8; ++r) {
        int c_l  = (tid >> 6) + r * 4;
        int hw_l = tid & 63;
        tile[hw_l][c_l] = x[((size_t)(b * CIN + c0 + c_l) << 12) + hw0 + hw_l];
    }
    __syncthreads();
    #pragma unroll
    for (int r = 0; r < 8; ++r) {
        int hw_l = (tid >> 5) + r * 8;
        int c_l  = tid & 31;
        xt[((size_t)(b * 4096 + hw0 + hw_l)) * CIN + c0 + c_l] = (__bf16)tile[hw_l][c_l];
    }
}

extern "C" void kernel_launch(void* const* d_in, const int* in_sizes, int n_in,
                              void* d_out, int out_size, void* d_ws, size_t ws_size,
                              hipStream_t stream) {
    const float* x   = (const float*)d_in[0];
    const float* off = (const float*)d_in[1];
    const float* w   = (const float*)d_in[2];
    float* out = (float*)d_out;

    const size_t wfrag_bytes = (size_t)OC * KTOT * sizeof(__bf16);        // 294912
    const size_t xt_bytes    = (size_t)4 * 4096 * CIN * sizeof(__bf16);   // 4 MB

    int mode = 0;
    if (ws_size >= wfrag_bytes + xt_bytes) mode = 3;
    else if (ws_size >= wfrag_bytes) mode = 1;

    __bf16* wfrag = (__bf16*)d_ws;
    __bf16* xt    = (__bf16*)((char*)d_ws + wfrag_bytes);

    if (mode == 3) {
        prep_kernel<<<PB_TOTAL, 256, 0, stream>>>(x, w, wfrag, xt);
        fullk_kernel<<<512, 256, 0, stream>>>(off, xt, wfrag, out);
    } else {
        if (mode >= 1)
            wfrag_kernel<<<(8 * KSTEPS * 64 + 255) / 256, 256, 0, stream>>>(w, wfrag);
        deform_fused_kernel<<<4 * 64 * 2 * 2, 512, 0, stream>>>(x, off, w, wfrag, xt, out, mode);
    }
}

// Round 2
// 83.720 us; speedup vs baseline: 1.1232x; 1.0123x over previous
//
#include <hip/hip_runtime.h>

// DeformConv2D b=4,c=128,H=W=64,outc=128,KS=3,PAD=1,N=9
// 2-launch pipeline (mode 3), round-7: f16 end-to-end staging + dbuf Bt:
//   prep  : wfrag32(f16) + xpose(f16) fused, branch on blockIdx (1096 blocks)
//   fullk : grid 512 = b4*i64*jh2 (XCD-swizzled), block = 32px x 128o,
//           256 thr (4 waves; wave = 32o x 32px via mfma_f32_32x32x16_f16).
//           Phase 0: all 288 descs computed inline -> LDS.
//           3 kh-phases, Bt double-buffered: stage(t+1) || mfma(t), one
//           barrier per phase. Staging math = half8 v_pk_fma_f16 (no bf16
//           unpack/repack): ~4x fewer VALU ops than round-6 bf16 path.
//           Epilogue: plain coalesced stores.
// Fallback (mode<=2): round-5 fused kernel (verified, bf16 16x16x32 path).

typedef __bf16  v8bf16 __attribute__((ext_vector_type(8)));
typedef __bf16  bf16x2 __attribute__((ext_vector_type(2)));
typedef float   f32x4  __attribute__((ext_vector_type(4)));
typedef float   f32x16 __attribute__((ext_vector_type(16)));
typedef unsigned short ushort4v __attribute__((ext_vector_type(4)));
typedef _Float16 half4v __attribute__((ext_vector_type(4)));
typedef _Float16 half8  __attribute__((ext_vector_type(8)));

#define CIN  128
#define NPT  9
#define KTOT 1152
#define OC   128
#define PX   32
#define NDESC (NPT * PX)     // 288
#define KSTEPS 36            // 16x16x32 steps (fallback layout)
#define KSC  12
#define LDBc 392
#define KS32 72              // 32x32x16 K-steps of 16 (mode-3 layout)
#define KSC32 24             // per kh
#define LDR32 392            // Bt row stride (f16 elems): 384 + 8

// prep grid layout
#define PB_WFRAG 72              // 72*256 = 18432 = 4*72*64
#define PB_XPOSE 1024
#define PB_TOTAL (PB_WFRAG + PB_XPOSE)

// geometry -> packed descriptor {idx4 u16, g4 f16}
__device__ __forceinline__ uint4 desc_make(const float* __restrict__ off,
                                           int b, int i, int j, int tap) {
    float ox = off[(((b * 18) + 2 * tap) << 12) + (i << 6) + j];
    float oy = off[(((b * 18) + 2 * tap + 1) << 12) + (i << 6) + j];
    float px = (float)(i + tap / 3) + ox;
    float py = (float)(j + tap % 3) + oy;
    float fx = floorf(px), fy = floorf(py);
    int qltx = (int)fminf(fmaxf(fx, 0.f), 65.f);
    int qlty = (int)fminf(fmaxf(fy, 0.f), 65.f);
    int qrbx = (int)fminf(fmaxf(fx + 1.f, 0.f), 65.f);
    int qrby = (int)fminf(fmaxf(fy + 1.f, 0.f), 65.f);
    if (px < 1.f || px > 64.f) px = fx;
    if (py < 1.f || py > 64.f) py = fy;
    px = fminf(fmaxf(px, 0.f), 65.f);
    py = fminf(fmaxf(py, 0.f), 65.f);
    float wxl = 1.f + (float)qltx - px;
    float wxr = 1.f - ((float)qrbx - px);
    float wyl = 1.f + (float)qlty - py;
    float wyr = 1.f - ((float)qrby - py);
    float g[4] = { wxl * wyl, wxr * wyr, wxl * wyr, wxr * wyl };
    int qx[4] = { qltx, qrbx, qltx, qrbx };
    int qy[4] = { qlty, qrby, qrby, qlty };
    unsigned short idx[4];
    half4v gh;
    #pragma unroll
    for (int cr = 0; cr < 4; ++cr) {
        bool inb = (qx[cr] >= 1) && (qx[cr] <= 64) && (qy[cr] >= 1) && (qy[cr] <= 64);
        idx[cr] = inb ? (unsigned short)((qx[cr] - 1) * 64 + (qy[cr] - 1)) : 0;
        gh[cr]  = inb ? (_Float16)g[cr] : (_Float16)0.f;
    }
    uint4 rec;
    rec.x = (unsigned)idx[0] | ((unsigned)idx[1] << 16);
    rec.y = (unsigned)idx[2] | ((unsigned)idx[3] << 16);
    __builtin_memcpy(&rec.z, &gh, 8);
    return rec;
}

// ---------- fused prep: wfrag32(f16) | xpose(f16) ----------
__global__ __launch_bounds__(256) void prep_kernel(
    const float* __restrict__ x, const float* __restrict__ w,
    _Float16* __restrict__ wfrag, _Float16* __restrict__ xt)
{
    __shared__ float tile[64][33];
    const int bid = blockIdx.x;
    const int tid = threadIdx.x;

    if (bid < PB_WFRAG) {
        // 32x32x16 A-frag layout: wfrag[((ot4*72+ks)*64+lane)*8+e]
        //   o = ot4*32 + (lane&31), k = ks*16 + (lane>>5)*8 + e
        int t = bid * 256 + tid;          // [0, 18432)
        int lane = t & 63;
        int ks   = (t >> 6) % KS32;
        int ot4  = t / (KS32 * 64);
        int o    = ot4 * 32 + (lane & 31);
        half8 frag;
        #pragma unroll
        for (int e = 0; e < 8; ++e) {
            int k   = ks * 16 + ((lane >> 5) * 8) + e;
            int tap = k >> 7, c = k & 127;
            frag[e] = (_Float16)w[(size_t)o * KTOT + c * NPT + tap];
        }
        *(half8*)(wfrag + (size_t)t * 8) = frag;
    } else {
        const int bidx = bid - PB_WFRAG;
        const int b   = bidx >> 8;
        const int hw0 = ((bidx >> 2) & 63) * 64;
        const int c0  = (bidx & 3) * 32;
        #pragma unroll
        for (int r = 0; r < 8; ++r) {
            int c_l  = (tid >> 6) + r * 4;
            int hw_l = tid & 63;
            tile[hw_l][c_l] = x[((size_t)(b * CIN + c0 + c_l) << 12) + hw0 + hw_l];
        }
        __syncthreads();
        #pragma unroll
        for (int r = 0; r < 8; ++r) {
            int hw_l = (tid >> 5) + r * 8;
            int c_l  = tid & 31;
            xt[((size_t)(b * 4096 + hw0 + hw_l)) * CIN + c0 + c_l] = (_Float16)tile[hw_l][c_l];
        }
    }
}

// ---------- full-K merged: inline desc, 3 kh-phases, f16 staging, dbuf Bt ----------
__global__ __launch_bounds__(256, 2) void fullk_kernel(
    const float* __restrict__ off, const _Float16* __restrict__ xt,
    const _Float16* __restrict__ wfrag, float* __restrict__ out)
{
    __shared__ __align__(16) _Float16 Bt[2][PX][LDR32]; // 2 x 32 x 392 f16 = 50176 B
    __shared__ __align__(16) uint4 sDesc[NDESC];        // 288 descs = 4608 B

    // XCD swizzle: b rides the low bits (2 XCDs per batch -> xt L2-resident)
    const int bidx = blockIdx.x;     // [0, 512)
    const int b    = (bidx & 7) >> 1;
    const int sub  = ((bidx >> 3) << 1) | (bidx & 1);   // [0, 128)
    const int i    = sub >> 1;
    const int j0   = (sub & 1) * PX;
    const int tid  = threadIdx.x;

    const int l  = tid & 63;
    const int wv = tid >> 6;            // 0..3 -> 32-o tile

    const _Float16* xtb = xt + (((size_t)b << 12) * CIN);

    // ---- phase 0: all 288 descs (9 taps x 32 px) computed inline -> LDS ----
    {
        sDesc[tid] = desc_make(off, b, i, j0 + (tid & 31), tid >> 5);
        if (tid < 32) sDesc[256 + tid] = desc_make(off, b, i, j0 + tid, 8);
    }
    __syncthreads();

    f32x16 acc = {0.f,0.f,0.f,0.f,0.f,0.f,0.f,0.f,0.f,0.f,0.f,0.f,0.f,0.f,0.f,0.f};
    const _Float16* warow = wfrag + (((size_t)wv * KS32) * 64 + l) * 8;

    const int q  = l >> 4;
    const int ll = l & 15;
    const _Float16* gbase = xtb + 8 * ll;

    // stage 96 descs of kh-phase t into buffer B: 24 per wave,
    // register-batched quarter-wave dwordx4 gathers, half8 pk-fma interp
    auto stage = [&](int t, _Float16 (*B)[LDR32]) {
        uint4 qd[6];
        int   pp[6], tt[6];
        #pragma unroll
        for (int m = 0; m < 6; ++m) {
            int dl = wv * 24 + m * 4 + q;    // [0,96) local
            tt[m] = dl >> 5;
            pp[m] = dl & 31;
            qd[m] = sDesc[t * 96 + dl];
        }
        #pragma unroll
        for (int h = 0; h < 2; ++h) {
            uint4  v[3][4];
            half4v gh[3];
            #pragma unroll
            for (int m = 0; m < 3; ++m) {
                uint4 qm = qd[h * 3 + m];
                unsigned int zz[2] = { qm.z, qm.w };
                __builtin_memcpy(&gh[m], &zz, 8);
                unsigned short idx[4] = {
                    (unsigned short)(qm.x & 0xffff), (unsigned short)(qm.x >> 16),
                    (unsigned short)(qm.y & 0xffff), (unsigned short)(qm.y >> 16) };
                #pragma unroll
                for (int cr = 0; cr < 4; ++cr)
                    v[m][cr] = *(const uint4*)(gbase + (size_t)idx[cr] * CIN);
            }
            #pragma unroll
            for (int m = 0; m < 3; ++m) {
                half8 s = {0, 0, 0, 0, 0, 0, 0, 0};
                #pragma unroll
                for (int cr = 0; cr < 4; ++cr) {
                    half8 vh;
                    __builtin_memcpy(&vh, &v[m][cr], 16);
                    s += vh * gh[m][cr];       // v_pk_fma_f16
                }
                int mm = h * 3 + m;
                *(half8*)&B[pp[mm]][tt[mm] * CIN + 8 * ll] = s;
            }
        }
    };

    stage(0, Bt[0]);
    __syncthreads();

    for (int t = 0; t < 3; ++t) {
        // issue next phase's staging first: its gathers/VALU overlap this
        // phase's MFMA across the co-resident waves (different buffer)
        if (t < 2) stage(t + 1, Bt[(t + 1) & 1]);

        // ---- MFMA: wave wv = o-tile [wv*32, wv*32+32) x px [j0, j0+32),
        //      24 K-steps of 16, acc carried across the 3 kh-phases ----
        const _Float16* brow = &Bt[t & 1][l & 31][(l >> 5) * 8];
        #pragma unroll 6
        for (int ks = 0; ks < KSC32; ++ks) {
            half8 afrag = *(const half8*)(warow + (size_t)(t * KSC32 + ks) * 64 * 8);
            half8 bfrag = *(const half8*)(brow + ks * 16);
            acc = __builtin_amdgcn_mfma_f32_32x32x16_f16(afrag, bfrag, acc, 0, 0, 0);
        }
        if (t < 2) __syncthreads();   // next buffer fully staged; this buffer free
    }

    // ---- epilogue: px = l&31, o = wv*32 + 4*(l>>5) + (reg&3) + 8*(reg>>2) ----
    {
        int obase = wv * 32 + 4 * (l >> 5);
        float* opb = out + (((size_t)(b * OC + obase)) << 12) + (i << 6) + j0 + (l & 31);
        #pragma unroll
        for (int reg = 0; reg < 16; ++reg) {
            int oo = (reg & 3) + 8 * (reg >> 2);
            opb[(size_t)oo << 12] = acc[reg];
        }
    }
}

// ---------- round-5 fused fallback (verified, bf16) ----------
__global__ __launch_bounds__(512, 8) void deform_fused_kernel(
    const float* __restrict__ x, const float* __restrict__ off,
    const float* __restrict__ w, const __bf16* __restrict__ wfrag,
    const __bf16* __restrict__ xt, float* __restrict__ out, int mode)
{
    __shared__ __align__(16) __bf16 Bt[PX][LDBc];
    __shared__ __align__(8)  unsigned short sIdxP[NDESC][4];
    __shared__ __align__(8)  _Float16      sGP[NDESC][4];

    const int bidx = blockIdx.x;
    const int b   = bidx >> 8;
    const int i   = (bidx >> 2) & 63;
    const int j0  = ((bidx >> 1) & 1) * PX;
    const int oh  = bidx & 1;
    const int tid = threadIdx.x;

    if (tid < NDESC) {
        int k = tid >> 5, p = tid & 31;
        int j = j0 + p;
        float ox = off[(((b * 18) + 2 * k) * 64 + i) * 64 + j];
        float oy = off[(((b * 18) + 2 * k + 1) * 64 + i) * 64 + j];
        float px = (float)(i + k / 3) + ox;
        float py = (float)(j + k % 3) + oy;
        float fx = floorf(px), fy = floorf(py);
        int qltx = (int)fminf(fmaxf(fx, 0.f), 65.f);
        int qlty = (int)fminf(fmaxf(fy, 0.f), 65.f);
        int qrbx = (int)fminf(fmaxf(fx + 1.f, 0.f), 65.f);
        int qrby = (int)fminf(fmaxf(fy + 1.f, 0.f), 65.f);
        if (px < 1.f || px > 64.f) px = fx;
        if (py < 1.f || py > 64.f) py = fy;
        px = fminf(fmaxf(px, 0.f), 65.f);
        py = fminf(fmaxf(py, 0.f), 65.f);
        float wxl = 1.f + (float)qltx - px;
        float wxr = 1.f - ((float)qrbx - px);
        float wyl = 1.f + (float)qlty - py;
        float wyr = 1.f - ((float)qrby - py);
        float g[4] = { wxl * wyl, wxr * wyr, wxl * wyr, wxr * wyl };
        int qx[4] = { qltx, qrbx, qltx, qrbx };
        int qy[4] = { qlty, qrby, qrby, qlty };
        #pragma unroll
        for (int cr = 0; cr < 4; ++cr) {
            bool inb = (qx[cr] >= 1) && (qx[cr] <= 64) && (qy[cr] >= 1) && (qy[cr] <= 64);
            sIdxP[tid][cr] = inb ? (unsigned short)((qx[cr] - 1) * 64 + (qy[cr] - 1)) : 0;
            sGP[tid][cr]   = inb ? (_Float16)g[cr] : (_Float16)0.f;
        }
    }
    __syncthreads();

    const int l    = tid & 63;
    const int wv   = tid >> 6;
    const int ot   = oh * 4 + (wv & 3);
    const int ph   = wv >> 2;
    const int quad = l >> 4;
    const int lr   = l & 15;

    f32x4 acc = {0.f, 0.f, 0.f, 0.f};
    const __bf16* xtb = xt + ((size_t)b * 4096) * CIN;
    const float*  xb  = x + ((size_t)b * CIN << 12);
    const __bf16* brow = &Bt[ph * 16 + lr][quad * 8];

    for (int t = 0; t < 3; ++t) {
        if (mode == 2) {
            #pragma unroll 4
            for (int dd = 0; dd < KSC; ++dd) {
                int dl = wv * KSC + dd;
                int tap_l = dl >> 5, p = dl & 31;
                int d = t * 96 + dl;
                ushort4v id = *(const ushort4v*)&sIdxP[d][0];
                half4v   gh = *(const half4v*)&sGP[d][0];
                float s0 = 0.f, s1 = 0.f;
                #pragma unroll
                for (int cr = 0; cr < 4; ++cr) {
                    unsigned int v = *(const unsigned int*)(xtb + (size_t)id[cr] * CIN + 2 * l);
                    float c0v, c1v;
                    unsigned int lo = v << 16, hi = v & 0xffff0000u;
                    __builtin_memcpy(&c0v, &lo, 4);
                    __builtin_memcpy(&c1v, &hi, 4);
                    float gf = (float)gh[cr];
                    s0 += gf * c0v;
                    s1 += gf * c1v;
                }
                bf16x2 pr = { (__bf16)s0, (__bf16)s1 };
                *(bf16x2*)&Bt[p][tap_l * CIN + 2 * l] = pr;
            }
        } else {
            for (int dd = 0; dd < KSC; ++dd) {
                int dl = wv * KSC + dd;
                int tap_l = dl >> 5, p = dl & 31;
                int d = t * 96 + dl;
                ushort4v id = *(const ushort4v*)&sIdxP[d][0];
                half4v   gh = *(const half4v*)&sGP[d][0];
                float s0 = 0.f, s1 = 0.f;
                #pragma unroll
                for (int cr = 0; cr < 4; ++cr) {
                    float gf = (float)gh[cr];
                    s0 += gf * xb[((size_t)(2 * l) << 12) + id[cr]];
                    s1 += gf * xb[((size_t)(2 * l + 1) << 12) + id[cr]];
                }
                bf16x2 pr = { (__bf16)s0, (__bf16)s1 };
                *(bf16x2*)&Bt[p][tap_l * CIN + 2 * l] = pr;
            }
        }
        __syncthreads();

        #pragma unroll 4
        for (int ks = 0; ks < KSC; ++ks) {
            int ks_g = t * KSC + ks;
            v8bf16 bfrag = *(const v8bf16*)(brow + ks * 32);
            v8bf16 afrag;
            if (mode >= 1) {
                afrag = *(const v8bf16*)(wfrag + (((size_t)ot * KSTEPS + ks_g) * 64 + l) * 8);
            } else {
                int o = ot * 16 + lr;
                #pragma unroll
                for (int e = 0; e < 8; ++e) {
                    int k = ks_g * 32 + quad * 8 + e;
                    int tap = k >> 7, c = k & 127;
                    afrag[e] = (__bf16)w[(size_t)o * KTOT + c * NPT + tap];
                }
            }
            acc = __builtin_amdgcn_mfma_f32_16x16x32_bf16(afrag, bfrag, acc, 0, 0, 0);
        }
        if (t < 2) __syncthreads();
    }

    {
        int obase = ot * 16 + quad * 4;
        float* op = out + (((size_t)(b * OC + obase)) << 12) + (i << 6) + j0 + ph * 16 + lr;
        #pragma unroll
        for (int r = 0; r < 4; ++r)
            op[(size_t)r << 12] = acc[r];
    }
}

// standalone prep pieces for fallback modes (old bf16 16x16x32 wfrag layout)
__global__ __launch_bounds__(256) void wfrag_kernel(const float* __restrict__ w,
                                                    __bf16* __restrict__ wfrag) {
    int t = blockIdx.x * 256 + threadIdx.x;
    if (t >= 8 * KSTEPS * 64) return;
    int lane = t & 63;
    int ks   = (t >> 6) % KSTEPS;
    int ot   = t / (KSTEPS * 64);
    int o    = ot * 16 + (lane & 15);
    v8bf16 frag;
    #pragma unroll
    for (int e = 0; e < 8; ++e) {
        int k   = ks * 32 + (lane >> 4) * 8 + e;
        int tap = k >> 7, c = k & 127;
        frag[e] = (__bf16)w[(size_t)o * KTOT + c * NPT + tap];
    }
    *(v8bf16*)(wfrag + (size_t)t * 8) = frag;
}

__global__ __launch_bounds__(256) void xpose_kernel(const float* __restrict__ x,
                                                    __bf16* __restrict__ xt) {
    __shared__ float tile[64][33];
    const int bidx = blockIdx.x;
    const int b   = bidx >> 8;
    const int hw0 = ((bidx >> 2) & 63) * 64;
    const int c0  = (bidx & 3) * 32;
    const int tid = threadIdx.x;
    #pragma unroll
    for (int r = 0; r < 8; ++r) {
        int c_l  = (tid >> 6) + r * 4;
        int hw_l = tid & 63;
        tile[hw_l][c_l] = x[((size_t)(b * CIN + c0 + c_l) << 12) + hw0 + hw_l];
    }
    __syncthreads();
    #pragma unroll
    for (int r = 0; r < 8; ++r) {
        int hw_l = (tid >> 5) + r * 8;
        int c_l  = tid & 31;
        xt[((size_t)(b * 4096 + hw0 + hw_l)) * CIN + c0 + c_l] = (__bf16)tile[hw_l][c_l];
    }
}

extern "C" void kernel_launch(void* const* d_in, const int* in_sizes, int n_in,
                              void* d_out, int out_size, void* d_ws, size_t ws_size,
                              hipStream_t stream) {
    const float* x   = (const float*)d_in[0];
    const float* off = (const float*)d_in[1];
    const float* w   = (const float*)d_in[2];
    float* out = (float*)d_out;

    const size_t wfrag_bytes = (size_t)OC * KTOT * 2;        // 294912 (f16/bf16)
    const size_t xt_bytes    = (size_t)4 * 4096 * CIN * 2;   // 4 MB

    int mode = 0;
    if (ws_size >= wfrag_bytes + xt_bytes) mode = 3;
    else if (ws_size >= wfrag_bytes) mode = 1;

    if (mode == 3) {
        _Float16* wfrag = (_Float16*)d_ws;
        _Float16* xt    = (_Float16*)((char*)d_ws + wfrag_bytes);
        prep_kernel<<<PB_TOTAL, 256, 0, stream>>>(x, w, wfrag, xt);
        fullk_kernel<<<512, 256, 0, stream>>>(off, xt, wfrag, out);
    } else {
        __bf16* wfrag = (__bf16*)d_ws;
        __bf16* xt    = (__bf16*)((char*)d_ws + wfrag_bytes);
        if (mode >= 1)
            wfrag_kernel<<<(8 * KSTEPS * 64 + 255) / 256, 256, 0, stream>>>(w, wfrag);
        deform_fused_kernel<<<4 * 64 * 2 * 2, 512, 0, stream>>>(x, off, w, wfrag, xt, out, mode);
    }
}